// Round 3
// baseline (195.892 us; speedup 1.0000x reference)
//
#include <hip/hip_runtime.h>
#include <hip/hip_bf16.h>

#define NB   32
#define CIN  128
#define COUT 256
#define HH   56
#define WW   56

typedef __attribute__((ext_vector_type(8))) short short8;   // 8 bf16 (4 VGPRs)
typedef __attribute__((ext_vector_type(4))) float f32x4;    // MFMA accumulator

// round-to-nearest-even fp32 -> bf16 (raw u16)
__device__ __forceinline__ unsigned short f2bf(float f) {
    unsigned int u = __builtin_bit_cast(unsigned int, f);
    u = u + 0x7fffu + ((u >> 16) & 1u);
    return (unsigned short)(u >> 16);
}

// async global->LDS, 16B per lane; LDS dest = wave-uniform base + lane*16
__device__ __forceinline__ void glds16(const unsigned short* g, unsigned short* l) {
    __builtin_amdgcn_global_load_lds(
        (const __attribute__((address_space(1))) unsigned int*)g,
        (__attribute__((address_space(3))) unsigned int*)l,
        16, 0, 0);
}

// ---------------------------------------------------------------------------
// Pre-pass 1: x NCHW f32 -> xt NHWC bf16  (xt[n][h][w][c])
// ---------------------------------------------------------------------------
__global__ __launch_bounds__(256) void xpose_kernel(const float* __restrict__ x,
                                                    unsigned short* __restrict__ xt) {
    __shared__ float tile[CIN][WW + 1];
    const int h = blockIdx.x, n = blockIdx.y;
    const float* src = x + ((size_t)n * CIN * HH + h) * WW;
    for (int i = threadIdx.x; i < CIN * WW; i += 256) {
        int c = i / WW, w = i - c * WW;
        tile[c][w] = src[(size_t)c * HH * WW + w];
    }
    __syncthreads();
    unsigned short* dst = xt + (size_t)(n * HH + h) * WW * CIN;
    for (int i = threadIdx.x; i < WW * (CIN / 2); i += 256) {
        int w = i / (CIN / 2), cp = i - w * (CIN / 2);
        unsigned int lo = f2bf(tile[2 * cp][w]);
        unsigned int hi = f2bf(tile[2 * cp + 1][w]);
        *(unsigned int*)&dst[w * CIN + 2 * cp] = lo | (hi << 16);
    }
}

// ---------------------------------------------------------------------------
// Pre-pass 2: w OIHW f32 -> wt [tap][o][c] bf16   (tap = kh*3+kw)
// ---------------------------------------------------------------------------
__global__ __launch_bounds__(256) void wpose_kernel(const float* __restrict__ w,
                                                    unsigned short* __restrict__ wt) {
    int g = blockIdx.x * 256 + threadIdx.x;     // g = (t*COUT + o)*CIN + c
    if (g >= 9 * COUT * CIN) return;
    int c = g & (CIN - 1);
    int o = (g >> 7) & (COUT - 1);
    int t = g >> 15;
    wt[g] = f2bf(w[(size_t)o * CIN * 9 + c * 9 + t]);
}

// ---------------------------------------------------------------------------
// Main conv. Block = 256 Cout x 64 w (one output row h), 4 waves of 64x64.
// B (x rows h-1..h+1, all 128 ch, wpos 0..57 incl. zero pads) staged ONCE:
//   ldsB[(kh*16+gc)*58 + wpos] : 16B chunk of 8 channels  (44544 B)
// A (weights) streamed per K-step (BK=32) via global_load_lds, double-buffered:
//   ldsA[buf][(g*256+o)*8] : 8 k-elems for k-group g, Cout row o (16384 B each)
// Both layouts: lane stride 16B -> start banks 4r mod 32 -> 2-way (free).
// One __syncthreads per K-step (issue next stage -> ds_read -> MFMA -> barrier).
// ---------------------------------------------------------------------------
__global__ __launch_bounds__(256) void conv_mfma_kernel(
        const unsigned short* __restrict__ xt,
        const unsigned short* __restrict__ wt,
        const float* __restrict__ bias,
        float* __restrict__ out) {
    __shared__ unsigned short ldsB[3 * 16 * 58 * 8];     // 44544 B
    __shared__ unsigned short ldsA[2][4 * 256 * 8];      // 2 x 16384 B

    const int tid  = threadIdx.x;
    const int h    = blockIdx.x, n = blockIdx.y;
    const int wid  = tid >> 6, lane = tid & 63;
    const int g    = lane >> 4, r = lane & 15;

    // ---- stage B once: 2784 16B chunks over 256 threads ----
    {
        const unsigned short* xbase = xt + (size_t)n * HH * WW * CIN;
        for (int i = tid; i < 3 * 16 * 58; i += 256) {
            int wpos = i % 58;
            int rest = i / 58;
            int gc = rest & 15;
            int kh = rest >> 4;
            int hs = h + kh - 1;
            int w  = wpos - 1;
            uint4 v = {0u, 0u, 0u, 0u};
            if ((unsigned)hs < HH && (unsigned)w < WW)
                v = *(const uint4*)&xbase[((size_t)hs * WW + w) * CIN + gc * 8];
            *(uint4*)&ldsB[(size_t)i * 8] = v;
        }
    }

    f32x4 acc[4][4];
    #pragma unroll
    for (int mi = 0; mi < 4; ++mi)
        #pragma unroll
        for (int ni = 0; ni < 4; ++ni)
            #pragma unroll
            for (int v = 0; v < 4; ++v) acc[mi][ni][v] = 0.f;

    const int KH[9] = {0,0,0,1,1,1,2,2,2};
    const int KW[9] = {0,1,2,0,1,2,0,1,2};

    // ---- A stage: step s (t = s>>2, cc = s&3); wave wid handles k-group g=wid
    #define STAGE_A(buf, s)                                                      \
        {                                                                        \
            const int t_ = (s) >> 2, cc_ = (s) & 3;                              \
            const unsigned short* wtap_ = wt + (size_t)t_ * COUT * CIN;          \
            _Pragma("unroll")                                                    \
            for (int i_ = 0; i_ < 4; ++i_) {                                     \
                const unsigned short* src_ =                                     \
                    wtap_ + (size_t)(i_ * 64 + lane) * CIN + cc_ * 32 + wid * 8; \
                glds16(src_, &ldsA[buf][(wid * 256 + i_ * 64) * 8]);             \
            }                                                                    \
        }

    STAGE_A(0, 0);
    __syncthreads();      // B writes + first A stage drained

    int cur = 0;
    for (int s = 0; s < 36; ++s) {
        if (s < 35) STAGE_A(cur ^ 1, s + 1);

        const int t  = s >> 2, cc = s & 3;
        const int kh = KH[t], kw = KW[t];

        short8 a[4], b[4];
        #pragma unroll
        for (int mi = 0; mi < 4; ++mi)
            a[mi] = *(const short8*)&ldsA[cur][(g * 256 + wid * 64 + mi * 16 + r) * 8];
        const int gc  = cc * 4 + g;
        const int bi0 = (kh * 16 + gc) * 58 + kw;   // wpos = w+1 = ni*16+r+kw
        #pragma unroll
        for (int ni = 0; ni < 4; ++ni)
            b[ni] = *(const short8*)&ldsB[(size_t)(bi0 + ni * 16 + r) * 8];

        #pragma unroll
        for (int mi = 0; mi < 4; ++mi)
            #pragma unroll
            for (int ni = 0; ni < 4; ++ni)
                acc[mi][ni] = __builtin_amdgcn_mfma_f32_16x16x32_bf16(
                    a[mi], b[ni], acc[mi][ni], 0, 0, 0);

        __syncthreads();   // drains this step's glds; frees cur buf for overwrite
        cur ^= 1;
    }

    // ---- epilogue: D col = r (w), row = g*4+v (within 16 of Cout) ----
    #pragma unroll
    for (int mi = 0; mi < 4; ++mi) {
        const int o0 = wid * 64 + mi * 16 + 4 * g;
        #pragma unroll
        for (int ni = 0; ni < 4; ++ni) {
            const int w = ni * 16 + r;
            if (w < WW) {
                #pragma unroll
                for (int v = 0; v < 4; ++v) {
                    const int o = o0 + v;
                    out[((size_t)(n * COUT + o) * HH + h) * WW + w] =
                        acc[mi][ni][v] + bias[o];
                }
            }
        }
    }
}

extern "C" void kernel_launch(void* const* d_in, const int* in_sizes, int n_in,
                              void* d_out, int out_size, void* d_ws, size_t ws_size,
                              hipStream_t stream) {
    const float* x  = (const float*)d_in[0];   // (32,128,56,56)
    const float* wk = (const float*)d_in[1];   // (256,128,3,3)
    const float* b  = (const float*)d_in[2];   // (256,)
    float* out = (float*)d_out;

    const size_t xt_elems = (size_t)NB * HH * WW * CIN;
    const size_t wt_elems = (size_t)9 * COUT * CIN;

    unsigned short* xt = (unsigned short*)d_ws;
    unsigned short* wt = xt + xt_elems;

    dim3 gx(HH, NB);
    xpose_kernel<<<gx, 256, 0, stream>>>(x, xt);
    wpose_kernel<<<(9 * COUT * CIN + 255) / 256, 256, 0, stream>>>(wk, wt);
    dim3 gc(HH, NB);
    conv_mfma_kernel<<<gc, 256, 0, stream>>>(xt, wt, b, out);
    (void)ws_size; (void)in_sizes; (void)n_in; (void)out_size;
}

// Round 5
// 87.784 us; speedup vs baseline: 2.2315x; 2.2315x over previous
//
#include <hip/hip_runtime.h>
#include <hip/hip_bf16.h>

#define NB   32
#define CIN  128
#define COUT 256
#define HH   56
#define WW   56

typedef __attribute__((ext_vector_type(8))) short short8;   // 8 bf16 (4 VGPRs)
typedef __attribute__((ext_vector_type(4))) float f32x4;    // MFMA accumulator

// round-to-nearest-even fp32 -> bf16 (raw u16)
__device__ __forceinline__ unsigned short f2bf(float f) {
    unsigned int u = __builtin_bit_cast(unsigned int, f);
    u = u + 0x7fffu + ((u >> 16) & 1u);
    return (unsigned short)(u >> 16);
}

// ---------------------------------------------------------------------------
// Pre-pass 1: x NCHW f32 -> xt NHWC bf16  (xt[n][h][w][c])
// ---------------------------------------------------------------------------
__global__ __launch_bounds__(256) void xpose_kernel(const float* __restrict__ x,
                                                    unsigned short* __restrict__ xt) {
    __shared__ float tile[CIN][WW + 1];
    const int h = blockIdx.x, n = blockIdx.y;
    const float* src = x + ((size_t)n * CIN * HH + h) * WW;
    for (int i = threadIdx.x; i < CIN * WW; i += 256) {
        int c = i / WW, w = i - c * WW;
        tile[c][w] = src[(size_t)c * HH * WW + w];
    }
    __syncthreads();
    unsigned short* dst = xt + (size_t)(n * HH + h) * WW * CIN;
    for (int i = threadIdx.x; i < WW * (CIN / 2); i += 256) {
        int w = i / (CIN / 2), cp = i - w * (CIN / 2);
        unsigned int lo = f2bf(tile[2 * cp][w]);
        unsigned int hi = f2bf(tile[2 * cp + 1][w]);
        *(unsigned int*)&dst[w * CIN + 2 * cp] = lo | (hi << 16);
    }
}

// ---------------------------------------------------------------------------
// Pre-pass 2: weights OIHW f32 -> wt2 in EXACT MFMA A-fragment order:
//   wt2[((s*16 + f)*64 + lane)*8 + j]
//   s = K-step (t = s>>2 tap, cc = s&3 channel-quad), f = 16-row M-fragment,
//   lane: g = lane>>4 (k-subgroup), r = lane&15 (row within fragment),
//   element = w[o = f*16 + r][c = cc*32 + g*8 + j][tap t]
// A wave's per-step fragment load is then ONE coalesced global_load_dwordx4.
// ---------------------------------------------------------------------------
__global__ __launch_bounds__(256) void wpose_kernel(const float* __restrict__ w,
                                                    unsigned short* __restrict__ wt2) {
    int q = blockIdx.x * 256 + threadIdx.x;    // element index
    if (q >= 36 * 16 * 64 * 8) return;
    int j = q & 7;
    int l = (q >> 3) & 63;
    int f = (q >> 9) & 15;
    int s = q >> 13;
    int g = l >> 4, r = l & 15;
    int t = s >> 2, cc = s & 3;
    int o = f * 16 + r;
    int c = cc * 32 + g * 8 + j;
    wt2[q] = f2bf(w[((size_t)o * CIN + c) * 9 + t]);
}

// ---------------------------------------------------------------------------
// Main conv: block = 256 Cout x 224 spatial (4 output rows h0..h0+3), 8 waves
// as 4(M) x 2(N); wave tile 64 x 112 = 4 x 7 fragments of 16x16 (NO padding
// waste: 224 = 14*16). K = 36 steps of 32 (9 taps x 4 channel-quads).
//   A: direct global fragment loads from wt2 (L1/L2-resident, 576 KB total,
//      identical stream for every block) -> no LDS, no double buffer.
//   B: x rows h0-1 .. h0+4 (6 rows x 128 ch x 58 wpos incl. zero pads) staged
//      ONCE into LDS: ldsB[((row*16 + gc)*58 + wpos)*8], 16B chunks -> all
//      reads/writes 2-way bank aliased = free.
// ZERO barriers in the K-loop -> compiler pipelines loads across steps.
// ---------------------------------------------------------------------------
__global__ __launch_bounds__(512) void conv_mfma_kernel(
        const unsigned short* __restrict__ xt,
        const unsigned short* __restrict__ wt2,
        const float* __restrict__ bias,
        float* __restrict__ out) {
    __shared__ unsigned short ldsB[6 * 16 * 58 * 8];    // 89088 B

    const int tid  = threadIdx.x;
    const int h0   = blockIdx.x * 4, n = blockIdx.y;
    const int wid  = tid >> 6, lane = tid & 63;
    const int wm   = wid >> 1, wn = wid & 1;            // 4M x 2N wave grid
    const int g    = lane >> 4, r = lane & 15;

    // ---- stage B once: 5568 16B chunks over 512 threads ----
    {
        const unsigned short* xbase = xt + (size_t)n * HH * WW * CIN;
        for (int i = tid; i < 6 * 16 * 58; i += 512) {
            int wpos = i % 58;
            int rest = i / 58;
            int gc  = rest & 15;
            int row = rest >> 4;            // 0..5 -> input row h0+row-1
            int hs  = h0 + row - 1;
            int w   = wpos - 1;
            uint4 v = {0u, 0u, 0u, 0u};
            if ((unsigned)hs < HH && (unsigned)w < WW)
                v = *(const uint4*)&xbase[((size_t)hs * WW + w) * CIN + gc * 8];
            *(uint4*)&ldsB[(size_t)i * 8] = v;
        }
    }
    __syncthreads();    // the only barrier

    // per-lane chunk offsets for the 7 N-fragments (col = ni*16 + r over 112
    // cols = 2 output rows x 56 w); row-split handled via +928 chunks (16*58)
    int lo[7];
    #pragma unroll
    for (int ni = 0; ni < 7; ++ni) {
        int c  = ni * 16 + r;
        int hr = (c >= 56) ? 1 : 0;
        lo[ni] = hr * (16 * 58) + (c - hr * 56);
    }

    f32x4 acc[4][7];
    #pragma unroll
    for (int mi = 0; mi < 4; ++mi)
        #pragma unroll
        for (int ni = 0; ni < 7; ++ni)
            #pragma unroll
            for (int v = 0; v < 4; ++v) acc[mi][ni][v] = 0.f;

    // wave's A base: fragment f = wm*4 + mi, index ((s*16+f)*64 + lane)
    const short8* abase = (const short8*)wt2 + (size_t)(wm * 4) * 64 + lane;

    #pragma unroll
    for (int t = 0; t < 9; ++t) {
        const int kh = t / 3, kw = t % 3;
        #pragma unroll
        for (int cc = 0; cc < 4; ++cc) {
            const int s  = t * 4 + cc;
            const int gc = cc * 4 + g;
            const int bb = (((wn * 2 + kh) * 16 + gc) * 58 + kw);

            short8 a[4];
            #pragma unroll
            for (int mi = 0; mi < 4; ++mi)
                a[mi] = abase[(size_t)s * 1024 + mi * 64];

            short8 b[7];
            #pragma unroll
            for (int ni = 0; ni < 7; ++ni)
                b[ni] = *(const short8*)&ldsB[(size_t)(bb + lo[ni]) * 8];

            #pragma unroll
            for (int mi = 0; mi < 4; ++mi)
                #pragma unroll
                for (int ni = 0; ni < 7; ++ni)
                    acc[mi][ni] = __builtin_amdgcn_mfma_f32_16x16x32_bf16(
                        a[mi], b[ni], acc[mi][ni], 0, 0, 0);
        }
    }

    // ---- epilogue: D col = r (spatial), row = g*4+v (Cout within frag) ----
    #pragma unroll
    for (int mi = 0; mi < 4; ++mi) {
        const int o0 = wm * 64 + mi * 16 + 4 * g;
        const float4 bv = *(const float4*)&bias[o0];
        #pragma unroll
        for (int ni = 0; ni < 7; ++ni) {
            const int c  = ni * 16 + r;
            const int hr = (c >= 56) ? 1 : 0;
            const int h  = h0 + wn * 2 + hr;
            const int w  = c - hr * 56;
            #pragma unroll
            for (int v = 0; v < 4; ++v) {
                out[((size_t)(n * COUT + o0 + v) * HH + h) * WW + w] =
                    acc[mi][ni][v] + ((const float*)&bv)[v];
            }
        }
    }
}

extern "C" void kernel_launch(void* const* d_in, const int* in_sizes, int n_in,
                              void* d_out, int out_size, void* d_ws, size_t ws_size,
                              hipStream_t stream) {
    const float* x  = (const float*)d_in[0];   // (32,128,56,56)
    const float* wk = (const float*)d_in[1];   // (256,128,3,3)
    const float* b  = (const float*)d_in[2];   // (256,)
    float* out = (float*)d_out;

    const size_t xt_elems = (size_t)NB * HH * WW * CIN;   // 12,845,056
    unsigned short* xt  = (unsigned short*)d_ws;
    unsigned short* wt2 = xt + xt_elems;                  // 294,912 elems

    dim3 gx(HH, NB);
    xpose_kernel<<<gx, 256, 0, stream>>>(x, xt);
    wpose_kernel<<<(36 * 16 * 64 * 8 + 255) / 256, 256, 0, stream>>>(wk, wt2);
    dim3 gc(14, NB);
    conv_mfma_kernel<<<gc, 512, 0, stream>>>(xt, wt2, b, out);
    (void)ws_size; (void)in_sizes; (void)n_in; (void)out_size;
}

// Round 6
// 77.406 us; speedup vs baseline: 2.5307x; 1.1341x over previous
//
#include <hip/hip_runtime.h>
#include <hip/hip_bf16.h>

#define NB   32
#define CIN  128
#define COUT 256
#define HH   56
#define WW   56

typedef __attribute__((ext_vector_type(8))) short short8;   // 8 bf16 (4 VGPRs)
typedef __attribute__((ext_vector_type(4))) float f32x4;    // MFMA accumulator

// round-to-nearest-even fp32 -> bf16 (raw u16)
__device__ __forceinline__ unsigned short f2bf(float f) {
    unsigned int u = __builtin_bit_cast(unsigned int, f);
    u = u + 0x7fffu + ((u >> 16) & 1u);
    return (unsigned short)(u >> 16);
}

// ---------------------------------------------------------------------------
// Pre-pass: weights OIHW f32 -> wt2 in EXACT MFMA A-fragment order:
//   wt2[((s*16 + f)*64 + lane)*8 + j]
//   s = K-step (t = s>>2 tap, cc = s&3 channel-quad), f = 16-row M-fragment,
//   lane: g = lane>>4 (k-subgroup), r = lane&15 (row within fragment),
//   element = w[o = f*16 + r][c = cc*32 + g*8 + j][tap t]
// A wave's per-step fragment load is ONE coalesced global_load_dwordx4,
// L1/L2-resident (576 KB total, identical stream for every block).
// ---------------------------------------------------------------------------
__global__ __launch_bounds__(256) void wpose_kernel(const float* __restrict__ w,
                                                    unsigned short* __restrict__ wt2) {
    int q = blockIdx.x * 256 + threadIdx.x;    // element index
    if (q >= 36 * 16 * 64 * 8) return;
    int j = q & 7;
    int l = (q >> 3) & 63;
    int f = (q >> 9) & 15;
    int s = q >> 13;
    int g = l >> 4, r = l & 15;
    int t = s >> 2, cc = s & 3;
    int o = f * 16 + r;
    int c = cc * 32 + g * 8 + j;
    wt2[q] = f2bf(w[((size_t)o * CIN + c) * 9 + t]);
}

// ---------------------------------------------------------------------------
// Main conv: block = 256 Cout x 224 spatial (4 output rows h0..h0+3),
// 1024 threads = 16 waves as 8(M) x 2(N); wave tile 32 x 112 = 2 x 7
// fragments of 16x16 (no padding waste). K = 36 steps of 32.
//   A: direct global fragment loads from wt2 -> no LDS, no barriers in K-loop.
//   B: x rows h0-1..h0+4 transposed NCHW f32 -> bf16 LDS **in-block** (fused,
//      no xt pre-pass): ldsB[((row*16 + gc)*58 + wpos)*8], wpos 0/57 + OOB
//      rows = zero pads. 16B chunks -> K-loop reads 2-way bank aliased (free).
// ---------------------------------------------------------------------------
__global__ __launch_bounds__(1024, 4) void conv_mfma_kernel(
        const float* __restrict__ x,
        const unsigned short* __restrict__ wt2,
        const float* __restrict__ bias,
        float* __restrict__ out) {
    __shared__ unsigned short ldsB[6 * 16 * 58 * 8];    // 89088 B

    const int tid  = threadIdx.x;
    const int h0   = blockIdx.x * 4, n = blockIdx.y;
    const int wid  = tid >> 6, lane = tid & 63;
    const int wm   = wid >> 1, wn = wid & 1;            // 8M x 2N wave grid
    const int g    = lane >> 4, r = lane & 15;

    // ---- zero all 5568 chunks (pads + OOB rows stay zero) ----
    for (int i = tid; i < 6 * 16 * 58; i += 1024) {
        uint4 z = {0u, 0u, 0u, 0u};
        *(uint4*)&ldsB[(size_t)i * 8] = z;
    }
    __syncthreads();

    // ---- fused transpose stage: NCHW f32 -> LDS bf16 ----
    // unit i = (row, cp, w4): channel-pair cp (c=2cp,2cp+1), float4 along w.
    {
        const float* xn = x + (size_t)n * CIN * HH * WW;
        for (int i = tid; i < 6 * 64 * 14; i += 1024) {
            int w4  = i % 14;
            int t1  = i / 14;
            int cp  = t1 & 63;
            int row = t1 >> 6;              // 0..5 -> input row h0+row-1
            int hs  = h0 + row - 1;
            if ((unsigned)hs < HH) {
                const float* src = xn + ((size_t)(2 * cp) * HH + hs) * WW + 4 * w4;
                float4 va = *(const float4*)src;
                float4 vb = *(const float4*)(src + HH * WW);
                int gc = cp >> 2, e = cp & 3;
                #pragma unroll
                for (int j = 0; j < 4; ++j) {
                    int wpos = 4 * w4 + j + 1;
                    unsigned int pk = (unsigned int)f2bf(((const float*)&va)[j])
                                    | ((unsigned int)f2bf(((const float*)&vb)[j]) << 16);
                    ((unsigned int*)ldsB)[((row * 16 + gc) * 58 + wpos) * 4 + e] = pk;
                }
            }
        }
    }
    __syncthreads();    // B ready; no more barriers

    // per-lane chunk offsets for the 7 N-fragments (col c = ni*16 + r within
    // this wave's 112-col half; row-split handled via +928 chunks = 16*58)
    int lo[7];
    #pragma unroll
    for (int ni = 0; ni < 7; ++ni) {
        int c  = ni * 16 + r;
        int hr = (c >= 56) ? 1 : 0;
        lo[ni] = hr * (16 * 58) + (c - hr * 56);
    }

    f32x4 acc[2][7];
    #pragma unroll
    for (int mi = 0; mi < 2; ++mi)
        #pragma unroll
        for (int ni = 0; ni < 7; ++ni)
            #pragma unroll
            for (int v = 0; v < 4; ++v) acc[mi][ni][v] = 0.f;

    // wave's A base: fragment f = wm*2 + mi, chunk ((s*16+f)*64 + lane)
    const short8* abase = (const short8*)wt2 + (size_t)(wm * 2) * 64 + lane;

    #pragma unroll
    for (int t = 0; t < 9; ++t) {
        const int kh = t / 3, kw = t % 3;
        #pragma unroll
        for (int cc = 0; cc < 4; ++cc) {
            const int s  = t * 4 + cc;
            const int gc = cc * 4 + g;
            const int bb = (((wn * 2 + kh) * 16 + gc) * 58 + kw);

            short8 a[2];
            #pragma unroll
            for (int mi = 0; mi < 2; ++mi)
                a[mi] = abase[(size_t)s * 1024 + mi * 64];

            short8 b[7];
            #pragma unroll
            for (int ni = 0; ni < 7; ++ni)
                b[ni] = *(const short8*)&ldsB[(size_t)(bb + lo[ni]) * 8];

            #pragma unroll
            for (int mi = 0; mi < 2; ++mi)
                #pragma unroll
                for (int ni = 0; ni < 7; ++ni)
                    acc[mi][ni] = __builtin_amdgcn_mfma_f32_16x16x32_bf16(
                        a[mi], b[ni], acc[mi][ni], 0, 0, 0);
        }
    }

    // ---- epilogue: D col = r (spatial), row = g*4+v (Cout within frag) ----
    #pragma unroll
    for (int mi = 0; mi < 2; ++mi) {
        const int o0 = wm * 32 + mi * 16 + 4 * g;
        const float4 bv = *(const float4*)&bias[o0];
        #pragma unroll
        for (int ni = 0; ni < 7; ++ni) {
            const int c  = ni * 16 + r;
            const int hr = (c >= 56) ? 1 : 0;
            const int h  = h0 + wn * 2 + hr;
            const int w  = c - hr * 56;
            #pragma unroll
            for (int v = 0; v < 4; ++v) {
                out[((size_t)(n * COUT + o0 + v) * HH + h) * WW + w] =
                    acc[mi][ni][v] + ((const float*)&bv)[v];
            }
        }
    }
}

extern "C" void kernel_launch(void* const* d_in, const int* in_sizes, int n_in,
                              void* d_out, int out_size, void* d_ws, size_t ws_size,
                              hipStream_t stream) {
    const float* x  = (const float*)d_in[0];   // (32,128,56,56)
    const float* wk = (const float*)d_in[1];   // (256,128,3,3)
    const float* b  = (const float*)d_in[2];   // (256,)
    float* out = (float*)d_out;

    unsigned short* wt2 = (unsigned short*)d_ws;   // 294,912 elems = 590 KB

    wpose_kernel<<<(36 * 16 * 64 * 8 + 255) / 256, 256, 0, stream>>>(wk, wt2);
    dim3 gc(14, NB);
    conv_mfma_kernel<<<gc, 1024, 0, stream>>>(x, wt2, b, out);
    (void)ws_size; (void)in_sizes; (void)n_in; (void)out_size;
}